// Round 9
// baseline (160.924 us; speedup 1.0000x reference)
//
#include <hip/hip_runtime.h>
#include <math.h>
#include <stdint.h>

#define VOCAB 100000
#define DIM   128
#define BATCH 16384
#define CMAX  10
#define KNEG  5
#define NSCORE (CMAX + KNEG)
#define SBLOCKS (BATCH / 4)   // 4096 score blocks, 4 samples (waves) each

typedef float f32x2 __attribute__((ext_vector_type(2)));

// Numerically stable log(sigmoid(x)) = min(x,0) - log1p(exp(-|x|))
__device__ __forceinline__ float log_sigmoid(float x) {
    return fminf(x, 0.0f) - log1pf(expf(-fabsf(x)));
}

// DPP 64-lane sum: 6 dependent VALU adds, total lands in lane 63.
#define DPP_ADD_STEP(v, ctrl)                                                  \
    v += __int_as_float(__builtin_amdgcn_update_dpp(                           \
        0, __float_as_int(v), (ctrl), 0xF, 0xF, false))

__device__ __forceinline__ float dpp_reduce64_to_lane63(float v) {
    DPP_ADD_STEP(v, 0x111);  // row_shr:1
    DPP_ADD_STEP(v, 0x112);  // row_shr:2
    DPP_ADD_STEP(v, 0x114);  // row_shr:4
    DPP_ADD_STEP(v, 0x118);  // row_shr:8   -> lanes 15/31/47/63 = row sums
    DPP_ADD_STEP(v, 0x142);  // row_bcast:15 -> lane31 += l15, lane63 += l47
    DPP_ADD_STEP(v, 0x143);  // row_bcast:31 -> lane63 += lane31 (full sum)
    return v;
}

// ---------------------------------------------------------------------------
// R9: one wave64 per sample, float2 per lane (512 B/row, single-row coalesced
// streams). 16 rows/sample = the structural byte floor (134 MB), barrier-free.
// b is wave-uniform -> all index loads compile to scalar s_load (contiguous
// ctx/neg rows), removing the index gather from the VMEM path. 16 row gathers
// asm-batched before one s_waitcnt vmcnt(0). Loss fused: lane 63 holds all 15
// reduced scores, computes the per-sample loss terms; block partials stored
// to d_ws (plain stores; 8192 same-address atomics would serialize).
// Grid: 4096 blocks x 256 threads = 16384 waves.
// ---------------------------------------------------------------------------
__global__ __launch_bounds__(256) void score_loss_kernel(
    const int*   __restrict__ tgt,
    const int*   __restrict__ ctx,
    const int*   __restrict__ lens,
    const int*   __restrict__ neg,
    const float* __restrict__ in_emb,
    const float* __restrict__ out_emb,
    float*       __restrict__ partial)   // [2 * SBLOCKS] in d_ws
{
    const int tid  = threadIdx.x;
    const int lane = tid & 63;
    const int wave = tid >> 6;                 // 0..3
    const int b    = blockIdx.x * 4 + wave;    // wave-uniform sample index

    // ---- wave-uniform index loads (compiler emits scalar s_load) ----
    const int t_word = tgt[b];
    const int len    = lens[b];
    int words[NSCORE];
#pragma unroll
    for (int c = 0; c < CMAX; ++c) words[c] = ctx[b * CMAX + c];
#pragma unroll
    for (int k = 0; k < KNEG; ++k) words[CMAX + k] = neg[b * KNEG + k];

    // ---- 16 row gathers (tv + 15 rv), all in flight before one waitcnt ----
    const uint32_t lane8 = (uint32_t)lane * 8u;

    f32x2 tv;
    {
        uint32_t off = (uint32_t)t_word * (DIM * 4u) + lane8;
        asm volatile("global_load_dwordx2 %0, %1, %2"
                     : "=v"(tv) : "v"(off), "s"(in_emb));
    }
    f32x2 rv[NSCORE];
#pragma unroll
    for (int j = 0; j < NSCORE; ++j) {
        uint32_t off = (uint32_t)words[j] * (DIM * 4u) + lane8;
        asm volatile("global_load_dwordx2 %0, %1, %2"
                     : "=v"(rv[j]) : "v"(off), "s"(out_emb));
    }
    asm volatile("s_waitcnt vmcnt(0)"
                 : "+v"(tv),
                   "+v"(rv[0]), "+v"(rv[1]), "+v"(rv[2]), "+v"(rv[3]),
                   "+v"(rv[4]), "+v"(rv[5]), "+v"(rv[6]), "+v"(rv[7]),
                   "+v"(rv[8]), "+v"(rv[9]), "+v"(rv[10]), "+v"(rv[11]),
                   "+v"(rv[12]), "+v"(rv[13]), "+v"(rv[14])
                 :
                 : "memory");

    // ---- 15 dots + 15 independent 64-lane DPP reductions ----
    float p[NSCORE];
#pragma unroll
    for (int j = 0; j < NSCORE; ++j) {
        float d = tv.x * rv[j].x + tv.y * rv[j].y;
        p[j] = dpp_reduce64_to_lane63(d);
    }

    // ---- fused loss on lane 63 (holds all 15 full sums) ----
    float pos_per = 0.0f, neg_per = 0.0f;
    if (lane == 63 && len > 0) {
        float pos_acc = 0.0f;
#pragma unroll
        for (int c = 0; c < CMAX; ++c)
            if (c < len) pos_acc += log_sigmoid(p[c]);
        float neg_acc = 0.0f;
#pragma unroll
        for (int k = 0; k < KNEG; ++k)
            neg_acc += log_sigmoid(-p[CMAX + k]);
        pos_per = -pos_acc / (float)len;
        neg_per = -neg_acc * (1.0f / KNEG);
    }

    // ---- block partials (4 waves) via LDS, plain stores to d_ws ----
    __shared__ float s_pos[4];
    __shared__ float s_neg[4];
    if (lane == 63) { s_pos[wave] = pos_per; s_neg[wave] = neg_per; }
    __syncthreads();
    if (tid == 0) {
        partial[blockIdx.x]           = s_pos[0] + s_pos[1] + s_pos[2] + s_pos[3];
        partial[SBLOCKS + blockIdx.x] = s_neg[0] + s_neg[1] + s_neg[2] + s_neg[3];
    }
}

// ---------------------------------------------------------------------------
// Finalize: one 256-thread block sums the 2*4096 partials and writes out[0..1]
// (overwrites -> no separate zero kernel needed for the 0xAA-poisoned d_out).
// ---------------------------------------------------------------------------
__global__ __launch_bounds__(256) void finalize_kernel(
    const float* __restrict__ partial,
    float*       __restrict__ out)
{
    const int tid = threadIdx.x;
    float ps = 0.0f, ns = 0.0f;
    for (int i = tid; i < SBLOCKS; i += 256) {
        ps += partial[i];
        ns += partial[SBLOCKS + i];
    }
#pragma unroll
    for (int m = 32; m >= 1; m >>= 1) {
        ps += __shfl_xor(ps, m, 64);
        ns += __shfl_xor(ns, m, 64);
    }
    __shared__ float s_pos[4];
    __shared__ float s_neg[4];
    const int wave = tid >> 6;
    if ((tid & 63) == 0) { s_pos[wave] = ps; s_neg[wave] = ns; }
    __syncthreads();
    if (tid == 0) {
        out[0] = (s_pos[0] + s_pos[1] + s_pos[2] + s_pos[3]) * (1.0f / BATCH);
        out[1] = (s_neg[0] + s_neg[1] + s_neg[2] + s_neg[3]) * (1.0f / BATCH);
    }
}

extern "C" void kernel_launch(void* const* d_in, const int* in_sizes, int n_in,
                              void* d_out, int out_size, void* d_ws, size_t ws_size,
                              hipStream_t stream) {
    const int*   tgt     = (const int*)  d_in[0];
    const int*   ctx     = (const int*)  d_in[1];
    const int*   lens    = (const int*)  d_in[2];
    const int*   neg     = (const int*)  d_in[3];
    const float* in_emb  = (const float*)d_in[4];
    const float* out_emb = (const float*)d_in[5];
    float* out     = (float*)d_out;
    float* partial = (float*)d_ws;      // 2 * 4096 floats = 32 KiB scratch

    score_loss_kernel<<<SBLOCKS, 256, 0, stream>>>(
        tgt, ctx, lens, neg, in_emb, out_emb, partial);

    finalize_kernel<<<1, 256, 0, stream>>>(partial, out);
}